// Round 9
// baseline (174.998 us; speedup 1.0000x reference)
//
#include <hip/hip_runtime.h>
#include <hip/hip_bf16.h>

// B=4, Q=K=512, D=512, H=256
#define HH 256
#define DD 512
#define MM 2048                       // B*Q == B*K flattened rows
#define CSCALE 2.8853900817779268f    // 2*log2(e), folded into W (linear)

typedef __bf16 bf16x8 __attribute__((ext_vector_type(8)));
typedef float floatx4 __attribute__((ext_vector_type(4)));

// ---------------------------------------------------------------------------
// prep: (a) blocks 0..255: transpose+scale Wq,Wk -> Wt[2][256][512] bf16
//       (b) block 256: wv2 = -2*wv, sumW = sum(wv)
//       (c) blocks 257..1280: convert queries||keys f32 -> Xbf bf16 [2M]
// ---------------------------------------------------------------------------
__global__ __launch_bounds__(256) void prep_kernel(
    const float* __restrict__ Wq, const float* __restrict__ Wk,
    const float* __restrict__ wv,
    const float* __restrict__ queries, const float* __restrict__ keys,
    __bf16* __restrict__ Wt, __bf16* __restrict__ Xbf,
    float* __restrict__ wv2, float* __restrict__ sumWp)
{
  const int bx = blockIdx.x;
  if (bx < 256) {
    const int mat  = bx >> 7;
    const int tile = bx & 127;
    const int kt = tile & 15;    // 512/32 k-tiles
    const int nt = tile >> 4;    // 256/32 n-tiles
    const float* __restrict__ W = mat ? Wk : Wq;
    __bf16* __restrict__ Wo = Wt + (size_t)mat * HH * DD;
    __shared__ float lds[32][33];
    const int i = threadIdx.x >> 5;   // 0..7
    const int j = threadIdx.x & 31;   // 0..31
    const int k0 = kt * 32, n0 = nt * 32;
#pragma unroll
    for (int p = 0; p < 4; ++p)
      lds[i + p * 8][j] = W[(k0 + i + p * 8) * HH + n0 + j];
    __syncthreads();
#pragma unroll
    for (int p = 0; p < 4; ++p) {
      const int n = i + p * 8;
      Wo[(n0 + n) * DD + k0 + j] = (__bf16)(lds[j][n] * CSCALE);
    }
  } else if (bx == 256) {
    __shared__ float red[256];
    const int t = threadIdx.x;
    float w = wv[t];
    wv2[t] = -2.0f * w;
    red[t] = w;
    __syncthreads();
    for (int s = 128; s > 0; s >>= 1) {
      if (t < s) red[t] += red[t + s];
      __syncthreads();
    }
    if (t == 0) *sumWp = red[0];
  } else {
    const int blk = bx - 257;                       // 0..1023
    const size_t dst = (size_t)blk * 2048 + threadIdx.x * 8;
    const float* __restrict__ src =
        (blk < 512) ? (queries + dst) : (keys + dst - (size_t)1048576);
    float4 a = *(const float4*)(src);
    float4 b = *(const float4*)(src + 4);
    bf16x8 v;
    v[0] = (__bf16)a.x; v[1] = (__bf16)a.y; v[2] = (__bf16)a.z; v[3] = (__bf16)a.w;
    v[4] = (__bf16)b.x; v[5] = (__bf16)b.y; v[6] = (__bf16)b.z; v[7] = (__bf16)b.w;
    *(bf16x8*)(Xbf + dst) = v;
  }
}

// ---------------------------------------------------------------------------
// proj: P = Xbf(2048x512 bf16) @ Wt^T (bf16, prescaled by 2*log2e).
// Block = 4 waves: wave (tw, ks) computes 16x32 tile tw over K-half ks.
// LDS combine, then exp2 epilogue:
//   z==0: queries -> eq = exp2(qc) f32  [2048][256]
//   z==1: keys    -> ek = exp2(kc) BF16 [64][2048][4] (h-quad packed, 1 MB)
// Fragment layouts (HW-verified rounds 1-8):
//   A: lane A[m=lane&15][k=(lane>>4)*8+j]; B: B[k=(lane>>4)*8+j][n=lane&15]
//   D: reg i -> row=(lane>>4)*4+i, col=lane&15
// ---------------------------------------------------------------------------
__global__ __launch_bounds__(256, 4) void proj_kernel(
    const __bf16* __restrict__ Xbf, const __bf16* __restrict__ Wt,
    float* __restrict__ eqp, __bf16* __restrict__ ekb)
{
  const int w    = threadIdx.x >> 6;
  const int lane = threadIdx.x & 63;
  const int quad = lane >> 4;
  const int r    = lane & 15;
  const int tw = w & 1;        // which 16-row tile
  const int ks = w >> 1;       // which K half
  const bool is_k = (blockIdx.z != 0);
  const __bf16* __restrict__ X  = Xbf + (is_k ? (size_t)1048576 : 0);
  const __bf16* __restrict__ Wb = Wt + (is_k ? (size_t)HH * DD : 0);

  const int m0 = blockIdx.x * 32 + tw * 16;
  const int n0 = blockIdx.y * 32;

  floatx4 acc0 = {0.f, 0.f, 0.f, 0.f};
  floatx4 acc1 = {0.f, 0.f, 0.f, 0.f};
  const __bf16* arow = X + (size_t)(m0 + r) * DD + ks * 256 + quad * 8;
  const __bf16* b0   = Wb + (size_t)(n0 + r) * DD + ks * 256 + quad * 8;
  const __bf16* b1   = b0 + 16 * DD;

#pragma unroll
  for (int kk = 0; kk < 256; kk += 32) {
    bf16x8 af  = *(const bf16x8*)(arow + kk);
    bf16x8 bf0 = *(const bf16x8*)(b0 + kk);
    bf16x8 bf1 = *(const bf16x8*)(b1 + kk);
    acc0 = __builtin_amdgcn_mfma_f32_16x16x32_bf16(af, bf0, acc0, 0, 0, 0);
    acc1 = __builtin_amdgcn_mfma_f32_16x16x32_bf16(af, bf1, acc1, 0, 0, 0);
  }

  __shared__ float part[2][64][9];   // +1 pad: conflict-free combine
  if (ks == 1) {
#pragma unroll
    for (int i = 0; i < 4; ++i) {
      part[tw][lane][i]     = acc0[i];
      part[tw][lane][4 + i] = acc1[i];
    }
  }
  __syncthreads();
  if (ks == 0) {
#pragma unroll
    for (int i = 0; i < 4; ++i) {
      acc0[i] += part[tw][lane][i];
      acc1[i] += part[tw][lane][4 + i];
    }
    const int mrow = m0 + quad * 4;
    if (!is_k) {
#pragma unroll
      for (int i = 0; i < 4; ++i) {
        eqp[(size_t)(mrow + i) * HH + n0 + r] =
            __builtin_amdgcn_exp2f(acc0[i]);
        eqp[(size_t)(mrow + i) * HH + n0 + 16 + r] =
            __builtin_amdgcn_exp2f(acc1[i]);
      }
    } else {
      const int na = n0 + r, nb = n0 + 16 + r;
#pragma unroll
      for (int i = 0; i < 4; ++i) {
        ekb[((size_t)(na >> 2) * MM + (mrow + i)) * 4 + (na & 3)] =
            (__bf16)__builtin_amdgcn_exp2f(acc0[i]);
        ekb[((size_t)(nb >> 2) * MM + (mrow + i)) * 4 + (nb & 3)] =
            (__bf16)__builtin_amdgcn_exp2f(acc1[i]);
      }
    }
  }
}

// ---------------------------------------------------------------------------
// score (R9): out[b,q,k] += partial over an h-HALF of
//   sumW + sum_{quads} [n01*p23 + n23*p01] * rcp(p01*p23)
//   u_i = 1 + eq*ek; n01 = w'0*u1 + w'1*u0; w' = -2*wv   (exact tanh algebra)
//
// R3-R8 lesson: score is VALU-ISSUE-bound (~11.25 cyc/wave-term at TQ=2);
// traffic/latency/operand-path changes were all neutral. This round cuts
// real issue to ~9.25 cyc/term via TQ=4 (amortizes ek unpack + addressing
// + loads over 16 terms) while KEEPING 2048 blocks = 8 waves/SIMD by
// splitting the h-range across 2 blocks (hb). Partials combine via
// unsafeAtomicAdd into memset-zeroed out (2-way same-address contention).
// Chunked unroll-4: 4 ek loads batched in flight, LDS reads imm-offset.
// ---------------------------------------------------------------------------
__device__ __forceinline__ float quad_term(
    float ek0, float ek1, float ek2, float ek3,
    float4 e, float4 w, float acc)
{
  float u0 = fmaf(e.x, ek0, 1.0f);
  float u1 = fmaf(e.y, ek1, 1.0f);
  float u2 = fmaf(e.z, ek2, 1.0f);
  float u3 = fmaf(e.w, ek3, 1.0f);
  float p01 = u0 * u1;
  float p23 = u2 * u3;
  float n01 = fmaf(w.y, u0, w.x * u1);
  float n23 = fmaf(w.w, u2, w.z * u3);
  float N   = fmaf(n23, p01, n01 * p23);
  float r   = __builtin_amdgcn_rcpf(p01 * p23);
  return fmaf(N, r, acc);
}

__global__ __launch_bounds__(256, 8) void score_kernel(
    const float* __restrict__ eqp, const uint2* __restrict__ ekb,
    const float* __restrict__ wv2, const float* __restrict__ sumWp,
    float* __restrict__ out)
{
  __shared__ __align__(16) float eqs[4][128];
  __shared__ __align__(16) float wvs[128];

  const int t  = threadIdx.x;
  const int b  = blockIdx.z;
  const int k  = blockIdx.x * 256 + t;
  const int qt = blockIdx.y >> 1;
  const int hb = blockIdx.y & 1;     // which h-half (128 of 256)
  const int q0 = qt * 4;

  // Stage 4 eq rows x 128-h half (2 KB) + wv2 half (512 B), coalesced.
  {
    int idx0 = t, idx1 = t + 256;
    eqs[idx0 >> 7][idx0 & 127] =
        eqp[(size_t)(b * 512 + q0 + (idx0 >> 7)) * HH + hb * 128 + (idx0 & 127)];
    eqs[idx1 >> 7][idx1 & 127] =
        eqp[(size_t)(b * 512 + q0 + (idx1 >> 7)) * HH + hb * 128 + (idx1 & 127)];
    if (t < 128) wvs[t] = wv2[hb * 128 + t];
  }
  const float sumW = (hb == 0) ? *sumWp : 0.0f;
  __syncthreads();

  const uint2* __restrict__ kptr =
      ekb + (size_t)(hb * 32) * MM + (size_t)b * 512 + k;

  float acc0 = 0.f, acc1 = 0.f, acc2 = 0.f, acc3 = 0.f;

  for (int c = 0; c < 8; ++c) {             // 8 chunks x 4 hq = 32 hq (half)
    uint2 kb[4];
#pragma unroll
    for (int i = 0; i < 4; ++i)             // 4 loads batched in flight
      kb[i] = kptr[(size_t)(c * 4 + i) * MM];
#pragma unroll
    for (int i = 0; i < 4; ++i) {
      const int hq = c * 4 + i;
      float ek0 = __uint_as_float(kb[i].x << 16);
      float ek1 = __uint_as_float(kb[i].x & 0xffff0000u);
      float ek2 = __uint_as_float(kb[i].y << 16);
      float ek3 = __uint_as_float(kb[i].y & 0xffff0000u);
      float4 w4 = *(const float4*)&wvs[hq * 4];      // ds_read imm offset
      acc0 = quad_term(ek0, ek1, ek2, ek3, *(const float4*)&eqs[0][hq * 4], w4, acc0);
      acc1 = quad_term(ek0, ek1, ek2, ek3, *(const float4*)&eqs[1][hq * 4], w4, acc1);
      acc2 = quad_term(ek0, ek1, ek2, ek3, *(const float4*)&eqs[2][hq * 4], w4, acc2);
      acc3 = quad_term(ek0, ek1, ek2, ek3, *(const float4*)&eqs[3][hq * 4], w4, acc3);
    }
  }

  float* obase = out + ((size_t)(b * 512 + q0)) * 512 + blockIdx.x * 256 + t;
  unsafeAtomicAdd(obase,        sumW + acc0);
  unsafeAtomicAdd(obase + 512,  sumW + acc1);
  unsafeAtomicAdd(obase + 1024, sumW + acc2);
  unsafeAtomicAdd(obase + 1536, sumW + acc3);
}

// ---------------------------------------------------------------------------
extern "C" void kernel_launch(void* const* d_in, const int* in_sizes, int n_in,
                              void* d_out, int out_size, void* d_ws, size_t ws_size,
                              hipStream_t stream) {
  (void)in_sizes; (void)n_in; (void)ws_size;
  const float* queries = (const float*)d_in[0];
  const float* Keys    = (const float*)d_in[1];
  const float* Wq      = (const float*)d_in[2];
  const float* Wk      = (const float*)d_in[3];
  const float* wv      = (const float*)d_in[4];
  float* out = (float*)d_out;

  // ws layout (~8 MB of the 256 MB workspace):
  //   [0, 512K)      Wt   bf16 [2][256][512]
  //   [512K, +1K)    wv2  f32 [256]  (= -2*wv)
  //   [513K, +4)     sumW
  //   [1M, 5M)       Xbf  bf16 [2][2048][512]  (queries||keys, converted)
  //   [5M, 7M)       eq   f32  [2048][256]
  //   [7M, 8M)       ekb  bf16 [64][2048][4]
  char* ws = (char*)d_ws;
  __bf16* Wt    = (__bf16*)ws;
  float*  wv2   = (float*)(ws + (512 << 10));
  float*  sumWp = (float*)(ws + (513 << 10));
  __bf16* Xbf   = (__bf16*)(ws + (1 << 20));
  float*  eqp   = (float*)(ws + (5ull << 20));
  __bf16* ekb   = (__bf16*)(ws + (7ull << 20));

  // out is poisoned 0xAA by the harness; score accumulates atomically.
  hipMemsetAsync(d_out, 0, (size_t)out_size * sizeof(float), stream);

  prep_kernel<<<dim3(1281), 256, 0, stream>>>(
      Wq, Wk, wv, queries, Keys, Wt, Xbf, wv2, sumWp);
  proj_kernel<<<dim3(64, 8, 2), 256, 0, stream>>>(Xbf, Wt, eqp, ekb);
  score_kernel<<<dim3(2, 256, 4), 256, 0, stream>>>(
      eqp, (const uint2*)ekb, wv2, sumWp, out);
}

// Round 10
// 107.412 us; speedup vs baseline: 1.6292x; 1.6292x over previous
//
#include <hip/hip_runtime.h>
#include <hip/hip_bf16.h>

// B=4, Q=K=512, D=512, H=256
#define HH 256
#define DD 512
#define MM 2048                       // B*Q == B*K flattened rows
#define CSCALE 2.8853900817779268f    // 2*log2(e), folded into W (linear)

typedef __bf16 bf16x8 __attribute__((ext_vector_type(8)));
typedef float floatx4 __attribute__((ext_vector_type(4)));

// ---------------------------------------------------------------------------
// prep: (a) blocks 0..255: transpose+scale Wq,Wk -> Wt[2][256][512] bf16
//       (b) block 256: wv2 = -2*wv, sumW = sum(wv)
//       (c) blocks 257..1280: convert queries||keys f32 -> Xbf bf16 [2M]
// ---------------------------------------------------------------------------
__global__ __launch_bounds__(256) void prep_kernel(
    const float* __restrict__ Wq, const float* __restrict__ Wk,
    const float* __restrict__ wv,
    const float* __restrict__ queries, const float* __restrict__ keys,
    __bf16* __restrict__ Wt, __bf16* __restrict__ Xbf,
    float* __restrict__ wv2, float* __restrict__ sumWp)
{
  const int bx = blockIdx.x;
  if (bx < 256) {
    const int mat  = bx >> 7;
    const int tile = bx & 127;
    const int kt = tile & 15;    // 512/32 k-tiles
    const int nt = tile >> 4;    // 256/32 n-tiles
    const float* __restrict__ W = mat ? Wk : Wq;
    __bf16* __restrict__ Wo = Wt + (size_t)mat * HH * DD;
    __shared__ float lds[32][33];
    const int i = threadIdx.x >> 5;   // 0..7
    const int j = threadIdx.x & 31;   // 0..31
    const int k0 = kt * 32, n0 = nt * 32;
#pragma unroll
    for (int p = 0; p < 4; ++p)
      lds[i + p * 8][j] = W[(k0 + i + p * 8) * HH + n0 + j];
    __syncthreads();
#pragma unroll
    for (int p = 0; p < 4; ++p) {
      const int n = i + p * 8;
      Wo[(n0 + n) * DD + k0 + j] = (__bf16)(lds[j][n] * CSCALE);
    }
  } else if (bx == 256) {
    __shared__ float red[256];
    const int t = threadIdx.x;
    float w = wv[t];
    wv2[t] = -2.0f * w;
    red[t] = w;
    __syncthreads();
    for (int s = 128; s > 0; s >>= 1) {
      if (t < s) red[t] += red[t + s];
      __syncthreads();
    }
    if (t == 0) *sumWp = red[0];
  } else {
    const int blk = bx - 257;                       // 0..1023
    const size_t dst = (size_t)blk * 2048 + threadIdx.x * 8;
    const float* __restrict__ src =
        (blk < 512) ? (queries + dst) : (keys + dst - (size_t)1048576);
    float4 a = *(const float4*)(src);
    float4 b = *(const float4*)(src + 4);
    bf16x8 v;
    v[0] = (__bf16)a.x; v[1] = (__bf16)a.y; v[2] = (__bf16)a.z; v[3] = (__bf16)a.w;
    v[4] = (__bf16)b.x; v[5] = (__bf16)b.y; v[6] = (__bf16)b.z; v[7] = (__bf16)b.w;
    *(bf16x8*)(Xbf + dst) = v;
  }
}

// ---------------------------------------------------------------------------
// proj: P = Xbf(2048x512 bf16) @ Wt^T (bf16, prescaled by 2*log2e).
// Block = 4 waves: wave (tw, ks) computes 16x32 tile tw over K-half ks.
// LDS combine, then exp2 epilogue:
//   z==0: queries -> eq = exp2(qc) f32  [2048][256]
//   z==1: keys    -> ek = exp2(kc) BF16 [m/16][hq(64)][m%16][4]
//         (16-k x 4-h 128B groups: score reads all 32 hq via IMM offsets)
// Fragment layouts (HW-verified rounds 1-9):
//   A: lane A[m=lane&15][k=(lane>>4)*8+j]; B: B[k=(lane>>4)*8+j][n=lane&15]
//   D: reg i -> row=(lane>>4)*4+i, col=lane&15
// ---------------------------------------------------------------------------
__global__ __launch_bounds__(256, 4) void proj_kernel(
    const __bf16* __restrict__ Xbf, const __bf16* __restrict__ Wt,
    float* __restrict__ eqp, __bf16* __restrict__ ekb)
{
  const int w    = threadIdx.x >> 6;
  const int lane = threadIdx.x & 63;
  const int quad = lane >> 4;
  const int r    = lane & 15;
  const int tw = w & 1;        // which 16-row tile
  const int ks = w >> 1;       // which K half
  const bool is_k = (blockIdx.z != 0);
  const __bf16* __restrict__ X  = Xbf + (is_k ? (size_t)1048576 : 0);
  const __bf16* __restrict__ Wb = Wt + (is_k ? (size_t)HH * DD : 0);

  const int m0 = blockIdx.x * 32 + tw * 16;
  const int n0 = blockIdx.y * 32;

  floatx4 acc0 = {0.f, 0.f, 0.f, 0.f};
  floatx4 acc1 = {0.f, 0.f, 0.f, 0.f};
  const __bf16* arow = X + (size_t)(m0 + r) * DD + ks * 256 + quad * 8;
  const __bf16* b0   = Wb + (size_t)(n0 + r) * DD + ks * 256 + quad * 8;
  const __bf16* b1   = b0 + 16 * DD;

#pragma unroll
  for (int kk = 0; kk < 256; kk += 32) {
    bf16x8 af  = *(const bf16x8*)(arow + kk);
    bf16x8 bf0 = *(const bf16x8*)(b0 + kk);
    bf16x8 bf1 = *(const bf16x8*)(b1 + kk);
    acc0 = __builtin_amdgcn_mfma_f32_16x16x32_bf16(af, bf0, acc0, 0, 0, 0);
    acc1 = __builtin_amdgcn_mfma_f32_16x16x32_bf16(af, bf1, acc1, 0, 0, 0);
  }

  __shared__ float part[2][64][9];   // +1 pad: conflict-free combine
  if (ks == 1) {
#pragma unroll
    for (int i = 0; i < 4; ++i) {
      part[tw][lane][i]     = acc0[i];
      part[tw][lane][4 + i] = acc1[i];
    }
  }
  __syncthreads();
  if (ks == 0) {
#pragma unroll
    for (int i = 0; i < 4; ++i) {
      acc0[i] += part[tw][lane][i];
      acc1[i] += part[tw][lane][4 + i];
    }
    const int mrow = m0 + quad * 4;
    if (!is_k) {
#pragma unroll
      for (int i = 0; i < 4; ++i) {
        eqp[(size_t)(mrow + i) * HH + n0 + r] =
            __builtin_amdgcn_exp2f(acc0[i]);
        eqp[(size_t)(mrow + i) * HH + n0 + 16 + r] =
            __builtin_amdgcn_exp2f(acc1[i]);
      }
    } else {
      const int na = n0 + r, nb = n0 + 16 + r;
#pragma unroll
      for (int i = 0; i < 4; ++i) {
        const int m = mrow + i;
        ekb[(((size_t)(m >> 4) * 64 + (na >> 2)) * 16 + (m & 15)) * 4 + (na & 3)] =
            (__bf16)__builtin_amdgcn_exp2f(acc0[i]);
        ekb[(((size_t)(m >> 4) * 64 + (nb >> 2)) * 16 + (m & 15)) * 4 + (nb & 3)] =
            (__bf16)__builtin_amdgcn_exp2f(acc1[i]);
      }
    }
  }
}

// ---------------------------------------------------------------------------
// score (R10): 512-thread blocks; waves 0-3 take h[0,128), waves 4-7 take
// h[128,256) for the SAME (k-tile, 4 q-rows). LDS combine (no atomics —
// R9 showed global atomics cause 54x write amplification).
//   out[b,q,k] = sumW + sum_{quads} [n01*p23 + n23*p01] * rcp(p01*p23)
//   u_i = 1 + eq*ek; n01 = w'0*u1 + w'1*u0; w' = -2*wv  (exact tanh algebra)
// ek layout [m/16][hq][m%16][4]: per-thread hq-stride = 128 B -> all 32
// loads are IMMEDIATE offsets off one base (no per-load address VALU);
// a wave's 64 lanes touch 4x128B segments per load (VMEM pipe fine).
// TQ=4 amortizes unpack/loads over 16 terms (~7.1 issue-cyc/wave-term).
// Grid (2,128,4) x 512 thr = 4 blocks/CU -> 8 waves/SIMD.
// ---------------------------------------------------------------------------
__device__ __forceinline__ float quad_term(
    float ek0, float ek1, float ek2, float ek3,
    float4 e, float4 w, float acc)
{
  float u0 = fmaf(e.x, ek0, 1.0f);
  float u1 = fmaf(e.y, ek1, 1.0f);
  float u2 = fmaf(e.z, ek2, 1.0f);
  float u3 = fmaf(e.w, ek3, 1.0f);
  float p01 = u0 * u1;
  float p23 = u2 * u3;
  float n01 = fmaf(w.y, u0, w.x * u1);
  float n23 = fmaf(w.w, u2, w.z * u3);
  float N   = fmaf(n23, p01, n01 * p23);
  float r   = __builtin_amdgcn_rcpf(p01 * p23);
  return fmaf(N, r, acc);
}

__global__ __launch_bounds__(512, 8) void score_kernel(
    const float* __restrict__ eqp, const uint2* __restrict__ ekb,
    const float* __restrict__ wv2, const float* __restrict__ sumWp,
    float* __restrict__ out)
{
  __shared__ __align__(16) float eqs[2][4][128];  // [hb][q-row][h]
  __shared__ __align__(16) float wvs[2][128];
  __shared__ __align__(16) float part[4][256];    // hb=1 partials

  const int tid = threadIdx.x;
  const int t   = tid & 255;          // k lane
  const int hb  = tid >> 8;           // h half (wave-uniform: waves 0-3 / 4-7)
  const int b   = blockIdx.z;
  const int k   = blockIdx.x * 256 + t;
  const int q0  = blockIdx.y * 4;

  // Stage eq (2 halves x 4 rows x 128 h = 4 KB) + wv2 (1 KB), coalesced.
  {
    const int i0 = tid, i1 = tid + 512;   // flat = hb2*512 + row*128 + col
    eqs[0][(i0 >> 7) & 3][i0 & 127] =
        eqp[(size_t)(b * 512 + q0 + ((i0 >> 7) & 3)) * HH + (i0 & 127)];
    eqs[1][(i1 >> 7) & 3][i1 & 127] =
        eqp[(size_t)(b * 512 + q0 + ((i1 >> 7) & 3)) * HH + 128 + (i1 & 127)];
    if (tid < 256) wvs[tid >> 7][tid & 127] = wv2[tid];
  }
  __syncthreads();

  const int m = b * 512 + k;            // global row in [0,2048)
  const uint2* __restrict__ kptr =
      ekb + ((size_t)(m >> 4) * 64 + hb * 32) * 16 + (m & 15);

  float acc0 = 0.f, acc1 = 0.f, acc2 = 0.f, acc3 = 0.f;

  for (int c = 0; c < 8; ++c) {         // 8 chunks x 4 hq = 32 hq per half
    uint2 kb[4];
#pragma unroll
    for (int i = 0; i < 4; ++i)         // all imm-offset, batched in flight
      kb[i] = kptr[(c * 4 + i) * 16];
#pragma unroll
    for (int i = 0; i < 4; ++i) {
      const int hq = c * 4 + i;
      float ek0 = __uint_as_float(kb[i].x << 16);
      float ek1 = __uint_as_float(kb[i].x & 0xffff0000u);
      float ek2 = __uint_as_float(kb[i].y << 16);
      float ek3 = __uint_as_float(kb[i].y & 0xffff0000u);
      float4 w4 = *(const float4*)&wvs[hb][hq * 4];    // ds broadcast
      acc0 = quad_term(ek0, ek1, ek2, ek3, *(const float4*)&eqs[hb][0][hq * 4], w4, acc0);
      acc1 = quad_term(ek0, ek1, ek2, ek3, *(const float4*)&eqs[hb][1][hq * 4], w4, acc1);
      acc2 = quad_term(ek0, ek1, ek2, ek3, *(const float4*)&eqs[hb][2][hq * 4], w4, acc2);
      acc3 = quad_term(ek0, ek1, ek2, ek3, *(const float4*)&eqs[hb][3][hq * 4], w4, acc3);
    }
  }

  if (hb == 1) {
    part[0][t] = acc0; part[1][t] = acc1;
    part[2][t] = acc2; part[3][t] = acc3;
  }
  __syncthreads();
  if (hb == 0) {
    const float sumW = *sumWp;
    float* obase = out + ((size_t)(b * 512 + q0)) * 512 + blockIdx.x * 256 + t;
    obase[0]    = sumW + acc0 + part[0][t];
    obase[512]  = sumW + acc1 + part[1][t];
    obase[1024] = sumW + acc2 + part[2][t];
    obase[1536] = sumW + acc3 + part[3][t];
  }
}

// ---------------------------------------------------------------------------
extern "C" void kernel_launch(void* const* d_in, const int* in_sizes, int n_in,
                              void* d_out, int out_size, void* d_ws, size_t ws_size,
                              hipStream_t stream) {
  (void)in_sizes; (void)n_in; (void)out_size; (void)ws_size;
  const float* queries = (const float*)d_in[0];
  const float* Keys    = (const float*)d_in[1];
  const float* Wq      = (const float*)d_in[2];
  const float* Wk      = (const float*)d_in[3];
  const float* wv      = (const float*)d_in[4];
  float* out = (float*)d_out;

  // ws layout (~8 MB of the 256 MB workspace):
  //   [0, 512K)      Wt   bf16 [2][256][512]
  //   [512K, +1K)    wv2  f32 [256]  (= -2*wv)
  //   [513K, +4)     sumW
  //   [1M, 5M)       Xbf  bf16 [2][2048][512]  (queries||keys, converted)
  //   [5M, 7M)       eq   f32  [2048][256]
  //   [7M, 8M)       ekb  bf16 [m/16][64][16][4]
  char* ws = (char*)d_ws;
  __bf16* Wt    = (__bf16*)ws;
  float*  wv2   = (float*)(ws + (512 << 10));
  float*  sumWp = (float*)(ws + (513 << 10));
  __bf16* Xbf   = (__bf16*)(ws + (1 << 20));
  float*  eqp   = (float*)(ws + (5ull << 20));
  __bf16* ekb   = (__bf16*)(ws + (7ull << 20));

  prep_kernel<<<dim3(1281), 256, 0, stream>>>(
      Wq, Wk, wv, queries, Keys, Wt, Xbf, wv2, sumWp);
  proj_kernel<<<dim3(64, 8, 2), 256, 0, stream>>>(Xbf, Wt, eqp, ekb);
  score_kernel<<<dim3(2, 128, 4), 512, 0, stream>>>(
      eqp, (const uint2*)ekb, wv2, sumWp, out);
}